// Round 7
// baseline (99.936 us; speedup 1.0000x reference)
//
#include <hip/hip_runtime.h>
#include <hip/hip_bf16.h>

typedef short bf16x8 __attribute__((ext_vector_type(8)));
typedef short bf16x4 __attribute__((ext_vector_type(4)));
typedef float f32x4 __attribute__((ext_vector_type(4)));
typedef _Float16 half4 __attribute__((ext_vector_type(4)));

__device__ __forceinline__ short f2bf(float f) {
    union { float f; unsigned u; } v; v.f = f;
    unsigned r = (v.u + 0x7FFFu + ((v.u >> 16) & 1u)) >> 16;
    return (short)r;
}

__device__ __forceinline__ float selu_f(float x) {
    const float scale = 1.0507009873554805f;
    const float sa = 1.0507009873554805f * 1.6732632423543772f;
    return x > 0.f ? scale * x : sa * (__expf(x) - 1.f);
}

__device__ __forceinline__ void gld_lds16(const char* g, char* l) {
    __builtin_amdgcn_global_load_lds(
        (const __attribute__((address_space(1))) unsigned int*)g,
        (__attribute__((address_space(3))) unsigned int*)l, 16, 0, 0);
}

// ---------------------------------------------------------------------------
// Kernel 1 (merged prep): blocks 0-511: cbias; 512-767: w1img; 768-783: wvec
// cbias[b][col] = ctr_f32(b) @ fW1[256:384,:] + fb1   (exact f32)
// w1img: W1[0:256,:] -> fragment-major bf16 image:
//   I = ((kc*32+cg)*64+lane)*8+e  <-  W1[kc*32+(lane>>4)*8+e][cg*16+(lane&15)]
// wvec: f16 B-table for 16x16x16 reduce-MFMA: col0=W21, col1=W22, rest 0
// ---------------------------------------------------------------------------
__global__ void __launch_bounds__(512) prep_all_kernel(
    const float* __restrict__ c, const int* __restrict__ lat_idx,
    const int* __restrict__ lon_idx,
    const float* __restrict__ f2W1, const float* __restrict__ f2b1,
    const float* __restrict__ f2W2, const float* __restrict__ f2b2,
    const float* __restrict__ fW1, const float* __restrict__ fb1,
    const float* __restrict__ fW21, const float* __restrict__ fW22,
    short* __restrict__ w1img, _Float16* __restrict__ wvec,
    float* __restrict__ cbias)
{
    const int bid = blockIdx.x;
    const int t = threadIdx.x;

    if (bid < 512) {
        __shared__ int cells[64];
        __shared__ float ctraj[128];
        __shared__ float hbuf[256];
        __shared__ float ctrf[128];
        const int b = bid;

        if (t < 64) cells[t] = lat_idx[b * 64 + t] * 17 + lon_idx[b * 64 + t];
        __syncthreads();

        if (t < 128) {
            float s = 0.f;
            #pragma unroll 8
            for (int j = 0; j < 64; ++j) s += c[t * 289 + cells[j]];
            ctraj[t] = s * (1.f / 64.f);
        }
        __syncthreads();

        if (t < 256) {
            float acc = f2b1[t];
            #pragma unroll 8
            for (int i = 0; i < 128; ++i) acc += ctraj[i] * f2W1[i * 256 + t];
            hbuf[t] = selu_f(acc);
        }
        __syncthreads();

        if (t < 128) {
            float acc = f2b2[t];
            #pragma unroll 8
            for (int i = 0; i < 256; ++i) acc += hbuf[i] * f2W2[i * 128 + t];
            ctrf[t] = acc;
        }
        __syncthreads();

        float acc = fb1[t];
        #pragma unroll 8
        for (int i = 0; i < 128; ++i) acc += ctrf[i] * fW1[(256 + i) * 512 + t];
        cbias[b * 512 + t] = acc;
    } else if (bid < 768) {
        int I = (bid - 512) * 512 + t;        // 0..131071
        int e = I & 7;
        int lane = (I >> 3) & 63;
        int cg = (I >> 9) & 31;
        int kc = I >> 14;
        int col = cg * 16 + (lane & 15);
        int k = kc * 32 + ((lane >> 4) << 3) + e;
        w1img[I] = f2bf(fW1[k * 512 + col]);
    } else {
        int I = (bid - 768) * 512 + t;        // 0..8191
        int e = I & 3;
        int lane = (I >> 2) & 63;
        int nc = I >> 8;
        int l15 = lane & 15, hi = lane >> 4;
        int n = nc * 16 + hi * 4 + e;
        float v = (l15 == 0) ? fW21[n] : (l15 == 1 ? fW22[n] : 0.f);
        wvec[I] = (_Float16)v;
    }
}

// ---------------------------------------------------------------------------
// Kernel 2: fused GEMM (K=256) + selu + MFMA reduce.
// 1024 blocks x 1024 threads (16 waves: 2 row-groups x 8 col-groups, 64x64).
// Block tile 128 rows x 512 cols, K in 8 chunks of 32.
// Triple-buffered LDS; B via global_load_lds; A via 1 float4/thread + cvt.
// Counted-vmcnt pipeline (2 chunks deep), raw s_barrier, no vmcnt(0) in loop.
// LDS: A 3x8KB @0 | B 3x32KB @24576 | redM 4KB @122880 | redV 4KB @126976
// ---------------------------------------------------------------------------
__global__ void __launch_bounds__(1024, 4) fused_gemm_kernel(
    const float* __restrict__ rho, const short* __restrict__ w1img,
    const float* __restrict__ cbias, const _Float16* __restrict__ wvec,
    float* __restrict__ plm, float* __restrict__ plv)
{
    __shared__ __align__(16) char smem[131072];

    const int tid  = threadIdx.x;
    const int lane = tid & 63;
    const int wid  = tid >> 6;     // 0..15
    const int wr   = wid >> 3;     // 0..1 row-group
    const int wc2  = wid & 7;      // 0..7 col-group
    const int l15  = lane & 15;
    const int hi   = lane >> 4;

    const int b  = blockIdx.x >> 1;
    const int s0 = (blockIdx.x & 1) << 7;

    // A staging mapping: thread t -> rg=t>>7, ln=(t>>1)&63, h=t&1
    const int rg_t = tid >> 7;
    const int ln_t = (tid >> 1) & 63;
    const int h_t  = tid & 1;
    const float* prA = rho + (size_t)(b * 256 + s0 + rg_t * 16 + (ln_t & 15)) * 256
                           + ((ln_t >> 4) << 3) + h_t * 4;
    const int awoff = ((rg_t * 64 + ln_t) << 4) + (h_t << 3);

    const char* wsrc = (const char*)w1img;

    f32x4 acc[4][4];
    #pragma unroll
    for (int nf = 0; nf < 4; ++nf)
        #pragma unroll
        for (int sf = 0; sf < 4; ++sf)
            acc[nf][sf] = (f32x4){0.f, 0.f, 0.f, 0.f};

    float4 pf0, pf1;

    // ---- prologue: issue batches 0 and 1 (B first, then A) ----
    {
        const char* bs0 = wsrc + (wid * 2) * 1024 + lane * 16;
        char* bd0 = smem + 24576 + (wid * 2) * 1024;
        gld_lds16(bs0, bd0);
        gld_lds16(bs0 + 1024, bd0 + 1024);
        pf0 = *(const float4*)(prA);
        const char* bs1 = wsrc + 32768 + (wid * 2) * 1024 + lane * 16;
        char* bd1 = smem + 24576 + 32768 + (wid * 2) * 1024;
        gld_lds16(bs1, bd1);
        gld_lds16(bs1 + 1024, bd1 + 1024);
        pf1 = *(const float4*)(prA + 8);
    }

#define CHUNK(I, PFX)                                                          \
    {                                                                          \
        { /* cvt+write A(I); compiler auto-waits vmcnt for PFX here */         \
          bf16x4 hh;                                                           \
          hh[0] = f2bf(PFX.x); hh[1] = f2bf(PFX.y);                            \
          hh[2] = f2bf(PFX.z); hh[3] = f2bf(PFX.w);                            \
          *(bf16x4*)(smem + ((I) % 3) * 8192 + awoff) = hh; }                  \
        if ((I) + 2 <= 7) { /* issue batch I+2: B gld_lds x2, then A load */   \
            const char* bs = wsrc + ((I) + 2) * 32768 + (wid * 2) * 1024       \
                             + lane * 16;                                      \
            char* bd = smem + 24576 + (((I) + 2) % 3) * 32768                  \
                       + (wid * 2) * 1024;                                     \
            gld_lds16(bs, bd);                                                 \
            gld_lds16(bs + 1024, bd + 1024);                                   \
            PFX = *(const float4*)(prA + ((I) + 2) * 8);                       \
        }                                                                      \
        asm volatile("s_waitcnt lgkmcnt(0)" ::: "memory");                     \
        __builtin_amdgcn_s_barrier();                                          \
        __builtin_amdgcn_sched_barrier(0);                                     \
        {                                                                      \
            bf16x8 aF[4], bF[4];                                               \
            const char* ab = smem + ((I) % 3) * 8192;                          \
            const char* bb = smem + 24576 + ((I) % 3) * 32768;                 \
            _Pragma("unroll")                                                  \
            for (int sf = 0; sf < 4; ++sf)                                     \
                aF[sf] = *(const bf16x8*)(ab + (((wr * 4 + sf) * 64 + lane) << 4)); \
            _Pragma("unroll")                                                  \
            for (int nf = 0; nf < 4; ++nf)                                     \
                bF[nf] = *(const bf16x8*)(bb + (((wc2 * 4 + nf) * 64 + lane) << 4)); \
            _Pragma("unroll")                                                  \
            for (int nf = 0; nf < 4; ++nf)                                     \
                _Pragma("unroll")                                              \
                for (int sf = 0; sf < 4; ++sf)                                 \
                    acc[nf][sf] = __builtin_amdgcn_mfma_f32_16x16x32_bf16(     \
                        bF[nf], aF[sf], acc[nf][sf], 0, 0, 0);                 \
        }                                                                      \
        __builtin_amdgcn_sched_barrier(0);                                     \
        __builtin_amdgcn_s_barrier();                                          \
    }

    CHUNK(0, pf0)
    CHUNK(1, pf1)
    CHUNK(2, pf0)
    CHUNK(3, pf1)
    CHUNK(4, pf0)
    CHUNK(5, pf1)
    CHUNK(6, pf0)
    CHUNK(7, pf1)
#undef CHUNK

    // ---- epilogue: selu(acc + cbias) -> f16 frags -> 16x16x16 reduce MFMA ----
    f32x4 rd[4];
    #pragma unroll
    for (int sf = 0; sf < 4; ++sf) rd[sf] = (f32x4){0.f, 0.f, 0.f, 0.f};

    #pragma unroll
    for (int nf = 0; nf < 4; ++nf) {
        f32x4 cbf = *(const f32x4*)(cbias + b * 512 + wc2 * 64 + nf * 16 + hi * 4);
        half4 wv = *(const half4*)(wvec + (size_t)(wc2 * 4 + nf) * 256 + lane * 4);
        #pragma unroll
        for (int sf = 0; sf < 4; ++sf) {
            half4 pa;
            #pragma unroll
            for (int q = 0; q < 4; ++q)
                pa[q] = (_Float16)selu_f(acc[nf][sf][q] + cbf[q]);
            rd[sf] = __builtin_amdgcn_mfma_f32_16x16x16f16(pa, wv, rd[sf], 0, 0, 0);
        }
    }

    float* redM = (float*)(smem + 122880);   // [8][128]
    float* redV = (float*)(smem + 126976);   // [8][128]
    if (l15 == 0) {
        #pragma unroll
        for (int sf = 0; sf < 4; ++sf)
            *(f32x4*)&redM[wc2 * 128 + wr * 64 + sf * 16 + hi * 4] = rd[sf];
    } else if (l15 == 1) {
        #pragma unroll
        for (int sf = 0; sf < 4; ++sf)
            *(f32x4*)&redV[wc2 * 128 + wr * 64 + sf * 16 + hi * 4] = rd[sf];
    }

    __syncthreads();
    size_t obase = (size_t)b * 256 + s0;
    if (tid < 128) {
        float s = 0.f;
        #pragma unroll
        for (int j = 0; j < 8; ++j) s += redM[j * 128 + tid];
        plm[obase + tid] = s;
    } else if (tid < 256) {
        int rr = tid - 128;
        float s = 0.f;
        #pragma unroll
        for (int j = 0; j < 8; ++j) s += redV[j * 128 + rr];
        plv[obase + rr] = s;
    }
}

// ---------------------------------------------------------------------------
// Kernel 3: per-b logsumexp over S=256 and final outputs (1 wave per b)
// ---------------------------------------------------------------------------
__global__ void __launch_bounds__(64) finalize_kernel(
    const float* __restrict__ plm, const float* __restrict__ plv,
    const float* __restrict__ w, const float* __restrict__ l,
    const float* __restrict__ b21p, const float* __restrict__ b22p,
    float* __restrict__ out)
{
    const int b = blockIdx.x;
    const int lane = threadIdx.x;
    const float b21 = b21p[0], b22 = b22p[0];

    float a1[4], a2[4];
    float m1 = -1e30f, m2 = -1e30f;
    #pragma unroll
    for (int i = 0; i < 4; ++i) {
        int s = i * 64 + lane;
        float lw = logf(w[b * 256 + s]);
        a1[i] = plm[b * 256 + s] + b21 + lw;
        a2[i] = plv[b * 256 + s] + b22 + 2.f * lw;
        m1 = fmaxf(m1, a1[i]);
        m2 = fmaxf(m2, a2[i]);
    }
    #pragma unroll
    for (int m = 1; m < 64; m <<= 1) {
        m1 = fmaxf(m1, __shfl_xor(m1, m));
        m2 = fmaxf(m2, __shfl_xor(m2, m));
    }
    float s1 = 0.f, s2 = 0.f;
    #pragma unroll
    for (int i = 0; i < 4; ++i) {
        s1 += expf(a1[i] - m1);
        s2 += expf(a2[i] - m2);
    }
    #pragma unroll
    for (int m = 1; m < 64; m <<= 1) {
        s1 += __shfl_xor(s1, m);
        s2 += __shfl_xor(s2, m);
    }
    if (lane == 0) {
        float lm_agg = m1 + logf(s1);
        float lv_agg = m2 + logf(s2);
        float logl = logf(l[b]);
        out[b]       = logl - lm_agg;
        out[512 + b] = logl - 3.f * lm_agg - lv_agg;
    }
}

extern "C" void kernel_launch(void* const* d_in, const int* in_sizes, int n_in,
                              void* d_out, int out_size, void* d_ws, size_t ws_size,
                              hipStream_t stream) {
    const float* rho     = (const float*)d_in[0];
    const float* c       = (const float*)d_in[1];
    const float* w       = (const float*)d_in[2];
    const float* l       = (const float*)d_in[3];
    // d_in[4] = roads (unused by the reference)
    const int*   lon_idx = (const int*)d_in[5];
    const int*   lat_idx = (const int*)d_in[6];
    const float* f2W1    = (const float*)d_in[7];
    const float* f2b1    = (const float*)d_in[8];
    const float* f2W2    = (const float*)d_in[9];
    const float* f2b2    = (const float*)d_in[10];
    const float* fW1     = (const float*)d_in[11];
    const float* fb1     = (const float*)d_in[12];
    const float* fW21    = (const float*)d_in[13];
    const float* fb21    = (const float*)d_in[14];
    const float* fW22    = (const float*)d_in[15];
    const float* fb22    = (const float*)d_in[16];
    float* out = (float*)d_out;

    char* ws = (char*)d_ws;
    float*     cbias = (float*)(ws);               // 1048576 B
    short*     w1img = (short*)(ws + 1048576);     //  262144 B
    float*     plm   = (float*)(ws + 1310720);     //  524288 B
    float*     plv   = (float*)(ws + 1835008);     //  524288 B
    _Float16*  wvec  = (_Float16*)(ws + 2359296);  //   16384 B

    prep_all_kernel<<<784, 512, 0, stream>>>(c, lat_idx, lon_idx,
                                             f2W1, f2b1, f2W2, f2b2,
                                             fW1, fb1, fW21, fW22,
                                             w1img, wvec, cbias);
    fused_gemm_kernel<<<1024, 1024, 0, stream>>>(rho, w1img, cbias, wvec,
                                                 plm, plv);
    finalize_kernel<<<512, 64, 0, stream>>>(plm, plv, w, l, fb21, fb22, out);
}